// Round 3
// baseline (477.895 us; speedup 1.0000x reference)
//
#include <hip/hip_runtime.h>
#include <float.h>
#include <math.h>

#define B_ 16
#define N_ 128
#define C_ 768
#define G_ 2000
#define CK_ 100
#define ALPHA_ 0.6f
#define EPS_ 1e-12f

typedef __attribute__((ext_vector_type(8))) short bf16x8;
typedef __attribute__((ext_vector_type(16))) float f32x16;

// ---------------- helpers ----------------
__device__ inline float wave_sum_lane0(float s) {
  #pragma unroll
  for (int off = 32; off > 0; off >>= 1) s += __shfl_down(s, off);
  return s;  // valid in lane 0
}
__device__ inline float wave_sum_all(float s) {
  #pragma unroll
  for (int off = 1; off < 64; off <<= 1) s += __shfl_xor(s, off);
  return s;
}

__device__ inline unsigned short bf16_rtn(float x) {
  unsigned u = __float_as_uint(x);
  u += 0x7fffu + ((u >> 16) & 1u);
  return (unsigned short)(u >> 16);
}
// split one float into hi/lo bf16 (RNE; identical numerics to validated R2 path)
__device__ inline void split2(float x, unsigned short& h, unsigned short& l) {
  h = bf16_rtn(x);
  float r = x - __uint_as_float(((unsigned)h) << 16);
  l = bf16_rtn(r);
}
// 8 consecutive floats (2 float4) -> bf16x8 hi + lo, accumulating square-sum
__device__ inline void split8(const float4& v0, const float4& v1,
                              bf16x8& h, bf16x8& l, float& sq) {
  float f[8] = {v0.x, v0.y, v0.z, v0.w, v1.x, v1.y, v1.z, v1.w};
  #pragma unroll
  for (int i = 0; i < 8; ++i) {
    float x = f[i];
    sq = fmaf(x, x, sq);
    unsigned short hh, ll;
    split2(x, hh, ll);
    h[i] = (short)hh;
    l[i] = (short)ll;
  }
}

// ---------------- inverse norms (one wave per 768-vector) ----------------
__global__ void invnorm_kernel(const float* __restrict__ src, float* __restrict__ inv, int nvec) {
  int wid = (blockIdx.x * blockDim.x + threadIdx.x) >> 6;
  int lane = threadIdx.x & 63;
  if (wid >= nvec) return;
  const float4* v = (const float4*)(src + (size_t)wid * C_);
  float s = 0.f;
  #pragma unroll
  for (int i = 0; i < 3; ++i) {
    float4 x = v[lane + 64 * i];
    s += x.x * x.x + x.y * x.y + x.z * x.z + x.w * x.w;
  }
  s = wave_sum_lane0(s);
  if (lane == 0) inv[wid] = 1.0f / fmaxf(sqrtf(s), EPS_);
}

// ---------------- normalize + presplit query patches (one wave per vector) ----------------
__global__ void qsplit_kernel(const float* __restrict__ qp,
                              unsigned short* __restrict__ qhi,
                              unsigned short* __restrict__ qlo) {
  int wid = (blockIdx.x * blockDim.x + threadIdx.x) >> 6;
  int lane = threadIdx.x & 63;
  if (wid >= B_ * N_) return;
  const float4* v = (const float4*)(qp + (size_t)wid * C_);
  float4 x0 = v[lane], x1 = v[lane + 64], x2 = v[lane + 128];
  float s = x0.x * x0.x + x0.y * x0.y + x0.z * x0.z + x0.w * x0.w
          + x1.x * x1.x + x1.y * x1.y + x1.z * x1.z + x1.w * x1.w
          + x2.x * x2.x + x2.y * x2.y + x2.z * x2.z + x2.w * x2.w;
  s = wave_sum_all(s);
  float inv = 1.0f / fmaxf(sqrtf(s), EPS_);
  float4 xs[3] = {x0, x1, x2};
  #pragma unroll
  for (int i = 0; i < 3; ++i) {
    float4 x = xs[i];
    x.x *= inv; x.y *= inv; x.z *= inv; x.w *= inv;
    ushort4 h, l;
    split2(x.x, h.x, l.x); split2(x.y, h.y, l.y);
    split2(x.z, h.z, l.z); split2(x.w, h.w, l.w);
    size_t off = (size_t)wid * C_ + (size_t)(lane + 64 * i) * 4;
    *(ushort4*)(qhi + off) = h;
    *(ushort4*)(qlo + off) = l;
  }
}

// ---------------- cls cosine distances: dall[b][g] ----------------
__global__ void clsdist_kernel(const float* __restrict__ gcls, const float* __restrict__ qcls,
                               const float* __restrict__ ginv, const float* __restrict__ qcinv,
                               float* __restrict__ dall) {
  int id = (blockIdx.x * blockDim.x + threadIdx.x) >> 6;
  int lane = threadIdx.x & 63;
  if (id >= B_ * G_) return;
  int b = id / G_, g = id - b * G_;
  const float4* gv = (const float4*)(gcls + (size_t)g * C_);
  const float4* qv = (const float4*)(qcls + (size_t)b * C_);
  float s = 0.f;
  #pragma unroll
  for (int i = 0; i < 3; ++i) {
    float4 x = gv[lane + 64 * i], y = qv[lane + 64 * i];
    s += x.x * y.x + x.y * y.y + x.z * y.z + x.w * y.w;
  }
  s = wave_sum_lane0(s);
  if (lane == 0) dall[id] = s * ginv[g] * qcinv[b];
}

// ---------------- top-100 per sample via full bitonic sort of 2048 packed keys -------------
// y = ~( key32(float) << 32 | (0xFFFFFFFF - idx) ); ascending-y == descending-(value, -idx)
// -> exact lax.top_k order (value desc, tie -> lower index).
__global__ void top100_kernel(const float* __restrict__ dall, int* __restrict__ cls_idx,
                              float* __restrict__ dsel) {
  __shared__ unsigned long long s[2048];
  int b = blockIdx.x, t = threadIdx.x;
  for (int i = t; i < 2048; i += 256) {
    unsigned long long y = 0xFFFFFFFFFFFFFFFFull;
    if (i < G_) {
      unsigned u = __float_as_uint(dall[b * G_ + i]);
      unsigned key = (u & 0x80000000u) ? ~u : (u | 0x80000000u);
      y = ~(((unsigned long long)key << 32) | (unsigned long long)(0xFFFFFFFFu - (unsigned)i));
    }
    s[i] = y;
  }
  __syncthreads();
  for (int k = 2; k <= 2048; k <<= 1) {
    for (int j = k >> 1; j > 0; j >>= 1) {
      for (int i = t; i < 2048; i += 256) {
        int l = i ^ j;
        if (l > i) {
          unsigned long long a = s[i], c = s[l];
          bool up = ((i & k) == 0);
          if ((a > c) == up) { s[i] = c; s[l] = a; }
        }
      }
      __syncthreads();
    }
  }
  for (int it = t; it < CK_; it += 256) {
    unsigned long long x = ~s[it];
    int idx = (int)(0xFFFFFFFFu - (unsigned)(x & 0xFFFFFFFFull));
    unsigned key = (unsigned)(x >> 32);
    unsigned u = (key & 0x80000000u) ? (key & 0x7FFFFFFFu) : ~key;
    cls_idx[b * CK_ + it] = idx;
    dsel[b * CK_ + it] = __uint_as_float(u);
  }
}

// ---------------- EMD kernel: one block per (b,k); LDS-free split-bf16 MFMA GEMM ------------
// A-frags come presplit (qhi/qlo, bf16, contiguous 16B loads). B-frags loaded fp32 (32B
// contiguous) and split in registers. No staging, no barriers in the K loop.
__global__ __launch_bounds__(256, 2) void emd_kernel(
    const unsigned short* __restrict__ qhi, const unsigned short* __restrict__ qlo,
    const float* __restrict__ gpat,
    const int* __restrict__ cls_idx, const float* __restrict__ dsel,
    float* __restrict__ dist) {
  __shared__ float red_row[128][2];
  __shared__ float red_col[128][2];
  __shared__ float bss[128];
  __shared__ float binv[128];

  // XCD-aware swizzle: blocks sharing b land on one XCD (A-side stays in that XCD's L2).
  int r = blockIdx.x;
  int xc = r & 7;
  int q = r >> 3;                       // 0..199
  int b = 2 * xc + (q >= CK_ ? 1 : 0);
  int k = (q >= CK_) ? (q - CK_) : q;
  int blk = b * CK_ + k;
  int g = cls_idx[blk];

  const float* Bptr = gpat + (size_t)g * (N_ * C_);

  int t = threadIdx.x;
  int lane = t & 63, wv = t >> 6;
  int wr = wv >> 1, wc = wv & 1;
  int l31 = lane & 31, lhi = lane >> 5;

  int rA0 = 64 * wr + l31, rA1 = rA0 + 32;
  int rB0 = 64 * wc + l31, rB1 = rB0 + 32;

  const unsigned short* pAh0 = qhi + ((size_t)(b * N_ + rA0)) * C_ + lhi * 8;
  const unsigned short* pAh1 = qhi + ((size_t)(b * N_ + rA1)) * C_ + lhi * 8;
  const unsigned short* pAl0 = qlo + ((size_t)(b * N_ + rA0)) * C_ + lhi * 8;
  const unsigned short* pAl1 = qlo + ((size_t)(b * N_ + rA1)) * C_ + lhi * 8;
  const float* pB0 = Bptr + (size_t)rB0 * C_ + lhi * 8;
  const float* pB1 = Bptr + (size_t)rB1 * C_ + lhi * 8;

  f32x16 acc00, acc01, acc10, acc11;
  #pragma unroll
  for (int e = 0; e < 16; ++e) { acc00[e] = 0.f; acc01[e] = 0.f; acc10[e] = 0.f; acc11[e] = 0.f; }

  float bsq0 = 0.f, bsq1 = 0.f;

  // current-tile registers
  bf16x8 cAh0[2], cAh1[2], cAl0[2], cAl1[2];
  float4 cB[8];  // [row*4 + ks*2 + half]
  #pragma unroll
  for (int ks = 0; ks < 2; ++ks) {
    cAh0[ks] = *(const bf16x8*)(pAh0 + ks * 16);
    cAh1[ks] = *(const bf16x8*)(pAh1 + ks * 16);
    cAl0[ks] = *(const bf16x8*)(pAl0 + ks * 16);
    cAl1[ks] = *(const bf16x8*)(pAl1 + ks * 16);
    cB[0 + ks * 2] = *(const float4*)(pB0 + ks * 16);
    cB[1 + ks * 2] = *(const float4*)(pB0 + ks * 16 + 4);
    cB[4 + ks * 2] = *(const float4*)(pB1 + ks * 16);
    cB[5 + ks * 2] = *(const float4*)(pB1 + ks * 16 + 4);
  }

  const int NT = C_ / 32;  // 24
  for (int kt = 0; kt < NT; ++kt) {
    bf16x8 nAh0[2], nAh1[2], nAl0[2], nAl1[2];
    float4 nB[8];
    if (kt + 1 < NT) {
      int o = (kt + 1) * 32;
      #pragma unroll
      for (int ks = 0; ks < 2; ++ks) {
        nAh0[ks] = *(const bf16x8*)(pAh0 + o + ks * 16);
        nAh1[ks] = *(const bf16x8*)(pAh1 + o + ks * 16);
        nAl0[ks] = *(const bf16x8*)(pAl0 + o + ks * 16);
        nAl1[ks] = *(const bf16x8*)(pAl1 + o + ks * 16);
        nB[0 + ks * 2] = *(const float4*)(pB0 + o + ks * 16);
        nB[1 + ks * 2] = *(const float4*)(pB0 + o + ks * 16 + 4);
        nB[4 + ks * 2] = *(const float4*)(pB1 + o + ks * 16);
        nB[5 + ks * 2] = *(const float4*)(pB1 + o + ks * 16 + 4);
      }
    }
    // split current B to bf16 hi/lo (VALU; overlaps next-tile load latency)
    bf16x8 bh0[2], bl0[2], bh1[2], bl1[2];
    #pragma unroll
    for (int ks = 0; ks < 2; ++ks) {
      split8(cB[0 + ks * 2], cB[1 + ks * 2], bh0[ks], bl0[ks], bsq0);
      split8(cB[4 + ks * 2], cB[5 + ks * 2], bh1[ks], bl1[ks], bsq1);
    }
    #pragma unroll
    for (int ks = 0; ks < 2; ++ks) {
      acc00 = __builtin_amdgcn_mfma_f32_32x32x16_bf16(cAh0[ks], bh0[ks], acc00, 0, 0, 0);
      acc00 = __builtin_amdgcn_mfma_f32_32x32x16_bf16(cAh0[ks], bl0[ks], acc00, 0, 0, 0);
      acc00 = __builtin_amdgcn_mfma_f32_32x32x16_bf16(cAl0[ks], bh0[ks], acc00, 0, 0, 0);
      acc01 = __builtin_amdgcn_mfma_f32_32x32x16_bf16(cAh0[ks], bh1[ks], acc01, 0, 0, 0);
      acc01 = __builtin_amdgcn_mfma_f32_32x32x16_bf16(cAh0[ks], bl1[ks], acc01, 0, 0, 0);
      acc01 = __builtin_amdgcn_mfma_f32_32x32x16_bf16(cAl0[ks], bh1[ks], acc01, 0, 0, 0);
      acc10 = __builtin_amdgcn_mfma_f32_32x32x16_bf16(cAh1[ks], bh0[ks], acc10, 0, 0, 0);
      acc10 = __builtin_amdgcn_mfma_f32_32x32x16_bf16(cAh1[ks], bl0[ks], acc10, 0, 0, 0);
      acc10 = __builtin_amdgcn_mfma_f32_32x32x16_bf16(cAl1[ks], bh0[ks], acc10, 0, 0, 0);
      acc11 = __builtin_amdgcn_mfma_f32_32x32x16_bf16(cAh1[ks], bh1[ks], acc11, 0, 0, 0);
      acc11 = __builtin_amdgcn_mfma_f32_32x32x16_bf16(cAh1[ks], bl1[ks], acc11, 0, 0, 0);
      acc11 = __builtin_amdgcn_mfma_f32_32x32x16_bf16(cAl1[ks], bh1[ks], acc11, 0, 0, 0);
    }
    if (kt + 1 < NT) {
      #pragma unroll
      for (int ks = 0; ks < 2; ++ks) {
        cAh0[ks] = nAh0[ks]; cAh1[ks] = nAh1[ks];
        cAl0[ks] = nAl0[ks]; cAl1[ks] = nAl1[ks];
        cB[0 + ks * 2] = nB[0 + ks * 2]; cB[1 + ks * 2] = nB[1 + ks * 2];
        cB[4 + ks * 2] = nB[4 + ks * 2]; cB[5 + ks * 2] = nB[5 + ks * 2];
      }
    }
  }

  // gallery patch inverse norms (rows rB0/rB1; lane pairs l, l^32 hold complementary halves)
  bsq0 += __shfl_xor(bsq0, 32);
  bsq1 += __shfl_xor(bsq1, 32);
  if (wr == 0 && lane < 32) {
    binv[64 * wc + lane]      = 1.0f / fmaxf(sqrtf(bsq0), EPS_);
    binv[64 * wc + 32 + lane] = 1.0f / fmaxf(sqrtf(bsq1), EPS_);
  }
  __syncthreads();
  float bi0 = binv[64 * wc + l31];
  float bi1 = binv[64 * wc + 32 + l31];

  // ---- row phase: per row n, max over cols m (scaled), reduce over lanes 0..31 ----
  {
    float rm[16];
    #pragma unroll
    for (int e = 0; e < 16; ++e) rm[e] = fmaxf(acc00[e] * bi0, acc01[e] * bi1);
    #pragma unroll
    for (int msk = 1; msk <= 16; msk <<= 1)
      #pragma unroll
      for (int e = 0; e < 16; ++e) rm[e] = fmaxf(rm[e], __shfl_xor(rm[e], msk));
    if (l31 == 0) {
      #pragma unroll
      for (int e = 0; e < 16; ++e)
        red_row[64 * wr + (e & 3) + 8 * (e >> 2) + 4 * lhi][wc] = rm[e];
    }
  }
  {
    float rm[16];
    #pragma unroll
    for (int e = 0; e < 16; ++e) rm[e] = fmaxf(acc10[e] * bi0, acc11[e] * bi1);
    #pragma unroll
    for (int msk = 1; msk <= 16; msk <<= 1)
      #pragma unroll
      for (int e = 0; e < 16; ++e) rm[e] = fmaxf(rm[e], __shfl_xor(rm[e], msk));
    if (l31 == 0) {
      #pragma unroll
      for (int e = 0; e < 16; ++e)
        red_row[64 * wr + 32 + (e & 3) + 8 * (e >> 2) + 4 * lhi][wc] = rm[e];
    }
  }
  // ---- col phase: per col m, max over rows n; scale by binv[m] after the max ----
  {
    float cm0 = -FLT_MAX, cm1 = -FLT_MAX;
    #pragma unroll
    for (int e = 0; e < 16; ++e) {
      cm0 = fmaxf(cm0, fmaxf(acc00[e], acc10[e]));
      cm1 = fmaxf(cm1, fmaxf(acc01[e], acc11[e]));
    }
    cm0 = fmaxf(cm0, __shfl_xor(cm0, 32)) * bi0;
    cm1 = fmaxf(cm1, __shfl_xor(cm1, 32)) * bi1;
    if (lane < 32) {
      red_col[64 * wc + lane][wr] = cm0;
      red_col[64 * wc + 32 + lane][wr] = cm1;
    }
  }
  __syncthreads();
  if (t < 128)
    bss[t] = fmaxf(red_row[t][0], red_row[t][1]) + fmaxf(red_col[t][0], red_col[t][1]);
  __syncthreads();
  if (t < 64) {
    float v = bss[t] + bss[t + 64];
    #pragma unroll
    for (int off = 32; off > 0; off >>= 1) v += __shfl_down(v, off);
    if (t == 0) {
      float emd = 0.5f * v * (1.0f / 128.0f);
      dist[blk] = ALPHA_ * dsel[blk] + (1.0f - ALPHA_) * emd;
    }
  }
}

// ---------------- final top-k (wave-parallel argmax) + cls mean ----------------
__global__ void sel10_kernel(const float* __restrict__ dist, const int* __restrict__ cls_idx,
                             const float* __restrict__ gcls, float* __restrict__ out_cls,
                             int* __restrict__ nb, int TK) {
  int b = blockIdx.x, t = threadIdx.x;
  __shared__ float v[128];
  __shared__ int snb[64];
  if (t < 128) v[t] = (t < CK_) ? dist[b * CK_ + t] : -FLT_MAX;
  __syncthreads();
  for (int j = 0; j < TK; ++j) {
    if (t < 64) {
      float v0 = v[t], v1 = v[t + 64];
      float bv; int bi;
      if (v0 >= v1) { bv = v0; bi = t; } else { bv = v1; bi = t + 64; }
      #pragma unroll
      for (int off = 1; off < 64; off <<= 1) {
        float ov = __shfl_xor(bv, off);
        int   oi = __shfl_xor(bi, off);
        if (ov > bv || (ov == bv && oi < bi)) { bv = ov; bi = oi; }
      }
      if (t == 0) {
        int gg = cls_idx[b * CK_ + bi];
        snb[j] = gg;
        nb[b * TK + j] = gg;
        v[bi] = -FLT_MAX;
      }
    }
    __syncthreads();
  }
  float invk = 1.0f / (float)TK;
  for (int c = t; c < C_; c += 256) {
    float s = 0.f;
    for (int j = 0; j < TK; ++j) s += gcls[(size_t)snb[j] * C_ + c];
    out_cls[(size_t)b * C_ + c] = s * invk;
  }
}

// ---------------- gather selected patches to output ----------------
__global__ void gather_kernel(const float* __restrict__ gpat, const int* __restrict__ nb,
                              float* __restrict__ out, int TK) {
  int i = blockIdx.x * blockDim.x + threadIdx.x;
  int per_vec = N_ * C_ / 4;       // float4s per gallery entry
  int per_b = TK * per_vec;
  int total = B_ * per_b;
  if (i >= total) return;
  int b = i / per_b;
  int r = i - b * per_b;
  int j = r / per_vec;
  int off = r - j * per_vec;
  int g = nb[b * TK + j];
  ((float4*)out)[i] = ((const float4*)gpat)[(size_t)g * per_vec + off];
}

extern "C" void kernel_launch(void* const* d_in, const int* in_sizes, int n_in,
                              void* d_out, int out_size, void* d_ws, size_t ws_size,
                              hipStream_t stream) {
  (void)in_sizes; (void)n_in; (void)ws_size;
  const float* qcls = (const float*)d_in[0];
  const float* qpat = (const float*)d_in[1];
  const float* gcls = (const float*)d_in[2];
  const float* gpat = (const float*)d_in[3];
  int TK = (out_size / B_ - C_) / (N_ * C_);  // = top_k (10)

  unsigned short* qhi = (unsigned short*)d_ws;               // B*N*C bf16 hi
  unsigned short* qlo = qhi + (size_t)B_ * N_ * C_;          // B*N*C bf16 lo
  float* dall  = (float*)(qlo + (size_t)B_ * N_ * C_);       // B*G
  float* ginv  = dall + B_ * G_;                             // G
  float* qcinv = ginv + G_;                                  // B (padded 16)
  float* dsel  = qcinv + 16;                                 // B*CK
  float* dist  = dsel + B_ * CK_;                            // B*CK
  int* cls_idx = (int*)(dist + B_ * CK_);                    // B*CK
  int* nb      = cls_idx + B_ * CK_;                         // B*TK

  hipLaunchKernelGGL(invnorm_kernel, dim3((G_ + 3) / 4), dim3(256), 0, stream, gcls, ginv, G_);
  hipLaunchKernelGGL(invnorm_kernel, dim3((B_ + 3) / 4), dim3(256), 0, stream, qcls, qcinv, B_);
  hipLaunchKernelGGL(qsplit_kernel, dim3(B_ * N_ / 4), dim3(256), 0, stream, qpat, qhi, qlo);
  hipLaunchKernelGGL(clsdist_kernel, dim3(B_ * G_ / 4), dim3(256), 0, stream,
                     gcls, qcls, ginv, qcinv, dall);
  hipLaunchKernelGGL(top100_kernel, dim3(B_), dim3(256), 0, stream, dall, cls_idx, dsel);
  hipLaunchKernelGGL(emd_kernel, dim3(B_ * CK_), dim3(256), 0, stream,
                     qhi, qlo, gpat, cls_idx, dsel, dist);
  float* out_cls = (float*)d_out + (size_t)B_ * TK * N_ * C_;
  hipLaunchKernelGGL(sel10_kernel, dim3(B_), dim3(256), 0, stream,
                     dist, cls_idx, gcls, out_cls, nb, TK);
  int total4 = B_ * TK * (N_ * C_ / 4);
  hipLaunchKernelGGL(gather_kernel, dim3((total4 + 255) / 256), dim3(256), 0, stream,
                     gpat, nb, (float*)d_out, TK);
}

// Round 5
// 301.171 us; speedup vs baseline: 1.5868x; 1.5868x over previous
//
#include <hip/hip_runtime.h>
#include <float.h>
#include <math.h>

#define B_ 16
#define N_ 128
#define C_ 768
#define G_ 2000
#define CK_ 100
#define ALPHA_ 0.6f
#define EPS_ 1e-12f

typedef __attribute__((ext_vector_type(8))) short bf16x8;
typedef __attribute__((ext_vector_type(16))) float f32x16;

// ---------------- helpers ----------------
__device__ inline float wave_sum_lane0(float s) {
  #pragma unroll
  for (int off = 32; off > 0; off >>= 1) s += __shfl_down(s, off);
  return s;  // valid in lane 0
}
__device__ inline float wave_sum_all(float s) {
  #pragma unroll
  for (int off = 1; off < 64; off <<= 1) s += __shfl_xor(s, off);
  return s;
}

__device__ inline unsigned short bf16_rtn(float x) {
  unsigned u = __float_as_uint(x);
  u += 0x7fffu + ((u >> 16) & 1u);
  return (unsigned short)(u >> 16);
}
// split one float into hi/lo bf16 (RNE) — validated R2 rounding path
__device__ inline void split2(float x, unsigned short& h, unsigned short& l) {
  h = bf16_rtn(x);
  float r = x - __uint_as_float(((unsigned)h) << 16);
  l = bf16_rtn(r);
}
// 8 consecutive floats -> packed hi uint4 + lo uint4 (RNE), accumulating sq-sum
__device__ inline void csplit8(const float4& v0, const float4& v1,
                               uint4& h, uint4& l, float& sq) {
  float f[8] = {v0.x, v0.y, v0.z, v0.w, v1.x, v1.y, v1.z, v1.w};
  unsigned short hh[8], ll[8];
  #pragma unroll
  for (int i = 0; i < 8; ++i) {
    float x = f[i];
    sq = fmaf(x, x, sq);
    split2(x, hh[i], ll[i]);
  }
  h.x = (unsigned)hh[0] | ((unsigned)hh[1] << 16);
  h.y = (unsigned)hh[2] | ((unsigned)hh[3] << 16);
  h.z = (unsigned)hh[4] | ((unsigned)hh[5] << 16);
  h.w = (unsigned)hh[6] | ((unsigned)hh[7] << 16);
  l.x = (unsigned)ll[0] | ((unsigned)ll[1] << 16);
  l.y = (unsigned)ll[2] | ((unsigned)ll[3] << 16);
  l.z = (unsigned)ll[4] | ((unsigned)ll[5] << 16);
  l.w = (unsigned)ll[6] | ((unsigned)ll[7] << 16);
}

// ---------------- fused prep: cls cosine distances + query patch norm/split ----------------
// blocks [0, B*G/4): one wave per (b,g) -> dall[b][g] = g.q / max(|g|,eps)/max(|q|,eps)
// blocks [B*G/4, +B*N/4): one wave per query-patch row -> normalize + bf16 hi/lo presplit
#define NCLSBLK_ (B_ * G_ / 4)
__global__ void prep_kernel(const float* __restrict__ gcls, const float* __restrict__ qcls,
                            const float* __restrict__ qp,
                            float* __restrict__ dall,
                            unsigned short* __restrict__ qhi, unsigned short* __restrict__ qlo) {
  int t = threadIdx.x;
  int lane = t & 63;
  if ((int)blockIdx.x < NCLSBLK_) {
    int id = ((int)blockIdx.x * 256 + t) >> 6;
    int b = id / G_, g = id - b * G_;
    const float4* gv = (const float4*)(gcls + (size_t)g * C_);
    const float4* qv = (const float4*)(qcls + (size_t)b * C_);
    float sgq = 0.f, sgg = 0.f, sqq = 0.f;
    #pragma unroll
    for (int i = 0; i < 3; ++i) {
      float4 x = gv[lane + 64 * i], y = qv[lane + 64 * i];
      sgq += x.x * y.x + x.y * y.y + x.z * y.z + x.w * y.w;
      sgg += x.x * x.x + x.y * x.y + x.z * x.z + x.w * x.w;
      sqq += y.x * y.x + y.y * y.y + y.z * y.z + y.w * y.w;
    }
    sgq = wave_sum_lane0(sgq);
    sgg = wave_sum_lane0(sgg);
    sqq = wave_sum_lane0(sqq);
    if (lane == 0) {
      float gi = 1.0f / fmaxf(sqrtf(sgg), EPS_);
      float qi = 1.0f / fmaxf(sqrtf(sqq), EPS_);
      dall[id] = sgq * gi * qi;
    }
  } else {
    int wid = (((int)blockIdx.x - NCLSBLK_) * 256 + t) >> 6;
    const float4* v = (const float4*)(qp + (size_t)wid * C_);
    float4 x0 = v[lane], x1 = v[lane + 64], x2 = v[lane + 128];
    float s = x0.x * x0.x + x0.y * x0.y + x0.z * x0.z + x0.w * x0.w
            + x1.x * x1.x + x1.y * x1.y + x1.z * x1.z + x1.w * x1.w
            + x2.x * x2.x + x2.y * x2.y + x2.z * x2.z + x2.w * x2.w;
    s = wave_sum_all(s);
    float inv = 1.0f / fmaxf(sqrtf(s), EPS_);
    float4 xs[3] = {x0, x1, x2};
    #pragma unroll
    for (int i = 0; i < 3; ++i) {
      float4 x = xs[i];
      x.x *= inv; x.y *= inv; x.z *= inv; x.w *= inv;
      ushort4 h, l;
      split2(x.x, h.x, l.x); split2(x.y, h.y, l.y);
      split2(x.z, h.z, l.z); split2(x.w, h.w, l.w);
      size_t off = (size_t)wid * C_ + (size_t)(lane + 64 * i) * 4;
      *(ushort4*)(qhi + off) = h;
      *(ushort4*)(qlo + off) = l;
    }
  }
}

// ---------------- top-100 per sample via full bitonic sort of 2048 packed keys -------------
// y = ~( key32(float) << 32 | (0xFFFFFFFF - idx) ); ascending-y == descending-(value, -idx)
// -> exact lax.top_k order (value desc, tie -> lower index).
__global__ void top100_kernel(const float* __restrict__ dall, int* __restrict__ cls_idx,
                              float* __restrict__ dsel) {
  __shared__ unsigned long long s[2048];
  int b = blockIdx.x, t = threadIdx.x;
  for (int i = t; i < 2048; i += 256) {
    unsigned long long y = 0xFFFFFFFFFFFFFFFFull;
    if (i < G_) {
      unsigned u = __float_as_uint(dall[b * G_ + i]);
      unsigned key = (u & 0x80000000u) ? ~u : (u | 0x80000000u);
      y = ~(((unsigned long long)key << 32) | (unsigned long long)(0xFFFFFFFFu - (unsigned)i));
    }
    s[i] = y;
  }
  __syncthreads();
  for (int k = 2; k <= 2048; k <<= 1) {
    for (int j = k >> 1; j > 0; j >>= 1) {
      for (int i = t; i < 2048; i += 256) {
        int l = i ^ j;
        if (l > i) {
          unsigned long long a = s[i], c = s[l];
          bool up = ((i & k) == 0);
          if ((a > c) == up) { s[i] = c; s[l] = a; }
        }
      }
      __syncthreads();
    }
  }
  for (int it = t; it < CK_; it += 256) {
    unsigned long long x = ~s[it];
    int idx = (int)(0xFFFFFFFFu - (unsigned)(x & 0xFFFFFFFFull));
    unsigned key = (unsigned)(x >> 32);
    unsigned u = (key & 0x80000000u) ? (key & 0x7FFFFFFFu) : ~key;
    cls_idx[b * CK_ + it] = idx;
    dsel[b * CK_ + it] = __uint_as_float(u);
  }
}

// ---------------- EMD kernel: one block per (b,k); LDS-staged split-bf16 MFMA GEMM ---------
// R2-validated structure. A staged as presplit bf16 (pure copy); B split in regs (RNE).
__global__ __launch_bounds__(256, 2) void emd_kernel(
    const unsigned short* __restrict__ qhi, const unsigned short* __restrict__ qlo,
    const float* __restrict__ gpat,
    const int* __restrict__ cls_idx, const float* __restrict__ dsel,
    float* __restrict__ dist) {
  __shared__ __align__(16) unsigned short sAhi[4096], sAlo[4096], sBhi[4096], sBlo[4096];
  __shared__ float red_row[128][2];
  __shared__ float red_col[128][2];
  __shared__ float bss[256];
  __shared__ float binv[128];

  // XCD-aware swizzle: blocks sharing b land on one XCD (A-side stays in that XCD's L2).
  int r = blockIdx.x;
  int xc = r & 7;
  int q = r >> 3;                       // 0..199
  int b = 2 * xc + (q >= CK_ ? 1 : 0);
  int k = (q >= CK_) ? (q - CK_) : q;
  int blk = b * CK_ + k;
  int g = cls_idx[blk];

  const float* Bptr = gpat + (size_t)g * (N_ * C_);

  int t = threadIdx.x;
  int lane = t & 63, wv = t >> 6;
  int wr = wv >> 1, wc = wv & 1;
  int l31 = lane & 31, lhi = lane >> 5;

  // staging assignment: thread t -> row m_st = t>>1, K-halfslot (t&1)*16 within 32-wide K tile
  int m_st = t >> 1, half = t & 1;
  const unsigned short* ahB = qhi + (size_t)(b * N_ + m_st) * C_ + half * 16;
  const unsigned short* alB = qlo + (size_t)(b * N_ + m_st) * C_ + half * 16;
  const float* bB = Bptr + (size_t)m_st * C_ + half * 16;
  int sw_st = (m_st >> 1) & 3;                       // 16B-slot swizzle for this row
  int e0 = m_st * 32 + (((2 * half + 0) ^ sw_st) << 3);
  int e1 = m_st * 32 + (((2 * half + 1) ^ sw_st) << 3);

  f32x16 acc00, acc01, acc10, acc11;
  #pragma unroll
  for (int e = 0; e < 16; ++e) { acc00[e] = 0.f; acc01[e] = 0.f; acc10[e] = 0.f; acc11[e] = 0.f; }

  // fragment rows/cols for this wave (K-map identical for A and B so HW K-permutation cancels)
  int rA0 = 64 * wr + l31, rA1 = rA0 + 32;
  int rB0 = 64 * wc + l31, rB1 = rB0 + 32;
  int swF = (l31 >> 1) & 3;                          // (row>>1)&3 for all four rows

  uint4 cah0, cah1, cal0, cal1;
  float4 cb0, cb1, cb2, cb3;
  cah0 = *(const uint4*)(ahB);     cah1 = *(const uint4*)(ahB + 8);
  cal0 = *(const uint4*)(alB);     cal1 = *(const uint4*)(alB + 8);
  cb0 = *(const float4*)(bB);      cb1 = *(const float4*)(bB + 4);
  cb2 = *(const float4*)(bB + 8);  cb3 = *(const float4*)(bB + 12);

  float bsq = 0.f;
  const int NT = C_ / 32;                            // 24 K-tiles
  for (int kt = 0; kt < NT; ++kt) {
    __syncthreads();                                 // previous MFMA phase done with LDS
    *(uint4*)&sAhi[e0] = cah0;  *(uint4*)&sAhi[e1] = cah1;
    *(uint4*)&sAlo[e0] = cal0;  *(uint4*)&sAlo[e1] = cal1;
    uint4 h, l;
    csplit8(cb0, cb1, h, l, bsq);
    *(uint4*)&sBhi[e0] = h;  *(uint4*)&sBlo[e0] = l;
    csplit8(cb2, cb3, h, l, bsq);
    *(uint4*)&sBhi[e1] = h;  *(uint4*)&sBlo[e1] = l;
    if (kt + 1 < NT) {                               // prefetch next tile (in flight during MFMA)
      int o = (kt + 1) * 32;
      cah0 = *(const uint4*)(ahB + o);      cah1 = *(const uint4*)(ahB + o + 8);
      cal0 = *(const uint4*)(alB + o);      cal1 = *(const uint4*)(alB + o + 8);
      cb0 = *(const float4*)(bB + o);       cb1 = *(const float4*)(bB + o + 4);
      cb2 = *(const float4*)(bB + o + 8);   cb3 = *(const float4*)(bB + o + 12);
    }
    __syncthreads();                                 // LDS tile ready
    #pragma unroll
    for (int ks = 0; ks < 2; ++ks) {
      int so = (((ks * 2 + lhi) ^ swF) << 3);
      bf16x8 ah0 = *(const bf16x8*)&sAhi[rA0 * 32 + so];
      bf16x8 al0 = *(const bf16x8*)&sAlo[rA0 * 32 + so];
      bf16x8 ah1 = *(const bf16x8*)&sAhi[rA1 * 32 + so];
      bf16x8 al1 = *(const bf16x8*)&sAlo[rA1 * 32 + so];
      bf16x8 bh0 = *(const bf16x8*)&sBhi[rB0 * 32 + so];
      bf16x8 bl0 = *(const bf16x8*)&sBlo[rB0 * 32 + so];
      bf16x8 bh1 = *(const bf16x8*)&sBhi[rB1 * 32 + so];
      bf16x8 bl1 = *(const bf16x8*)&sBlo[rB1 * 32 + so];
      acc00 = __builtin_amdgcn_mfma_f32_32x32x16_bf16(ah0, bh0, acc00, 0, 0, 0);
      acc00 = __builtin_amdgcn_mfma_f32_32x32x16_bf16(ah0, bl0, acc00, 0, 0, 0);
      acc00 = __builtin_amdgcn_mfma_f32_32x32x16_bf16(al0, bh0, acc00, 0, 0, 0);
      acc01 = __builtin_amdgcn_mfma_f32_32x32x16_bf16(ah0, bh1, acc01, 0, 0, 0);
      acc01 = __builtin_amdgcn_mfma_f32_32x32x16_bf16(ah0, bl1, acc01, 0, 0, 0);
      acc01 = __builtin_amdgcn_mfma_f32_32x32x16_bf16(al0, bh1, acc01, 0, 0, 0);
      acc10 = __builtin_amdgcn_mfma_f32_32x32x16_bf16(ah1, bh0, acc10, 0, 0, 0);
      acc10 = __builtin_amdgcn_mfma_f32_32x32x16_bf16(ah1, bl0, acc10, 0, 0, 0);
      acc10 = __builtin_amdgcn_mfma_f32_32x32x16_bf16(al1, bh0, acc10, 0, 0, 0);
      acc11 = __builtin_amdgcn_mfma_f32_32x32x16_bf16(ah1, bh1, acc11, 0, 0, 0);
      acc11 = __builtin_amdgcn_mfma_f32_32x32x16_bf16(ah1, bl1, acc11, 0, 0, 0);
      acc11 = __builtin_amdgcn_mfma_f32_32x32x16_bf16(al1, bh1, acc11, 0, 0, 0);
    }
  }

  // gallery-patch inverse norms (from squared sums accumulated during staging)
  bss[t] = bsq;
  __syncthreads();
  if (t < 128) {
    float s = bss[2 * t] + bss[2 * t + 1];
    binv[t] = 1.0f / fmaxf(sqrtf(s), EPS_);
  }
  __syncthreads();
  float bi0 = binv[64 * wc + l31];
  float bi1 = binv[64 * wc + 32 + l31];

  // ---- row phase: per row n, max over cols m (scaled), reduce over lanes 0..31 ----
  {
    float rm[16];
    #pragma unroll
    for (int e = 0; e < 16; ++e) rm[e] = fmaxf(acc00[e] * bi0, acc01[e] * bi1);
    #pragma unroll
    for (int msk = 1; msk <= 16; msk <<= 1)
      #pragma unroll
      for (int e = 0; e < 16; ++e) rm[e] = fmaxf(rm[e], __shfl_xor(rm[e], msk));
    if (l31 == 0) {
      #pragma unroll
      for (int e = 0; e < 16; ++e)
        red_row[64 * wr + (e & 3) + 8 * (e >> 2) + 4 * lhi][wc] = rm[e];
    }
  }
  {
    float rm[16];
    #pragma unroll
    for (int e = 0; e < 16; ++e) rm[e] = fmaxf(acc10[e] * bi0, acc11[e] * bi1);
    #pragma unroll
    for (int msk = 1; msk <= 16; msk <<= 1)
      #pragma unroll
      for (int e = 0; e < 16; ++e) rm[e] = fmaxf(rm[e], __shfl_xor(rm[e], msk));
    if (l31 == 0) {
      #pragma unroll
      for (int e = 0; e < 16; ++e)
        red_row[64 * wr + 32 + (e & 3) + 8 * (e >> 2) + 4 * lhi][wc] = rm[e];
    }
  }
  // ---- col phase: per col m, max over rows n; scale by binv[m] after the max ----
  {
    float cm0 = -FLT_MAX, cm1 = -FLT_MAX;
    #pragma unroll
    for (int e = 0; e < 16; ++e) {
      cm0 = fmaxf(cm0, fmaxf(acc00[e], acc10[e]));
      cm1 = fmaxf(cm1, fmaxf(acc01[e], acc11[e]));
    }
    cm0 = fmaxf(cm0, __shfl_xor(cm0, 32)) * bi0;
    cm1 = fmaxf(cm1, __shfl_xor(cm1, 32)) * bi1;
    if (lane < 32) {
      red_col[64 * wc + lane][wr] = cm0;
      red_col[64 * wc + 32 + lane][wr] = cm1;
    }
  }
  __syncthreads();
  if (t < 128)
    bss[t] = fmaxf(red_row[t][0], red_row[t][1]) + fmaxf(red_col[t][0], red_col[t][1]);
  __syncthreads();
  if (t < 64) {
    float v = bss[t] + bss[t + 64];
    #pragma unroll
    for (int off = 32; off > 0; off >>= 1) v += __shfl_down(v, off);
    if (t == 0) {
      float emd = 0.5f * v * (1.0f / 128.0f);
      dist[blk] = ALPHA_ * dsel[blk] + (1.0f - ALPHA_) * emd;
    }
  }
}

// ---------------- final top-k (wave-parallel argmax) + cls mean ----------------
__global__ void sel10_kernel(const float* __restrict__ dist, const int* __restrict__ cls_idx,
                             const float* __restrict__ gcls, float* __restrict__ out_cls,
                             int* __restrict__ nb, int TK) {
  int b = blockIdx.x, t = threadIdx.x;
  __shared__ float v[128];
  __shared__ int snb[64];
  if (t < 128) v[t] = (t < CK_) ? dist[b * CK_ + t] : -FLT_MAX;
  __syncthreads();
  for (int j = 0; j < TK; ++j) {
    if (t < 64) {
      float v0 = v[t], v1 = v[t + 64];
      float bv; int bi;
      if (v0 >= v1) { bv = v0; bi = t; } else { bv = v1; bi = t + 64; }
      #pragma unroll
      for (int off = 1; off < 64; off <<= 1) {
        float ov = __shfl_xor(bv, off);
        int   oi = __shfl_xor(bi, off);
        if (ov > bv || (ov == bv && oi < bi)) { bv = ov; bi = oi; }
      }
      if (t == 0) {
        int gg = cls_idx[b * CK_ + bi];
        snb[j] = gg;
        nb[b * TK + j] = gg;
        v[bi] = -FLT_MAX;
      }
    }
    __syncthreads();
  }
  float invk = 1.0f / (float)TK;
  for (int c = t; c < C_; c += 256) {
    float s = 0.f;
    for (int j = 0; j < TK; ++j) s += gcls[(size_t)snb[j] * C_ + c];
    out_cls[(size_t)b * C_ + c] = s * invk;
  }
}

// ---------------- gather selected patches to output ----------------
__global__ void gather_kernel(const float* __restrict__ gpat, const int* __restrict__ nb,
                              float* __restrict__ out, int TK) {
  int i = blockIdx.x * blockDim.x + threadIdx.x;
  int per_vec = N_ * C_ / 4;       // float4s per gallery entry
  int per_b = TK * per_vec;
  int total = B_ * per_b;
  if (i >= total) return;
  int b = i / per_b;
  int r = i - b * per_b;
  int j = r / per_vec;
  int off = r - j * per_vec;
  int g = nb[b * TK + j];
  ((float4*)out)[i] = ((const float4*)gpat)[(size_t)g * per_vec + off];
}

extern "C" void kernel_launch(void* const* d_in, const int* in_sizes, int n_in,
                              void* d_out, int out_size, void* d_ws, size_t ws_size,
                              hipStream_t stream) {
  (void)in_sizes; (void)n_in; (void)ws_size;
  const float* qcls = (const float*)d_in[0];
  const float* qpat = (const float*)d_in[1];
  const float* gcls = (const float*)d_in[2];
  const float* gpat = (const float*)d_in[3];
  int TK = (out_size / B_ - C_) / (N_ * C_);  // = top_k (10)

  unsigned short* qhi = (unsigned short*)d_ws;               // B*N*C bf16 hi
  unsigned short* qlo = qhi + (size_t)B_ * N_ * C_;          // B*N*C bf16 lo
  float* dall  = (float*)(qlo + (size_t)B_ * N_ * C_);       // B*G
  float* dsel  = dall + B_ * G_;                             // B*CK
  float* dist  = dsel + B_ * CK_;                            // B*CK
  int* cls_idx = (int*)(dist + B_ * CK_);                    // B*CK
  int* nb      = cls_idx + B_ * CK_;                         // B*TK

  hipLaunchKernelGGL(prep_kernel, dim3(NCLSBLK_ + B_ * N_ / 4), dim3(256), 0, stream,
                     gcls, qcls, qpat, dall, qhi, qlo);
  hipLaunchKernelGGL(top100_kernel, dim3(B_), dim3(256), 0, stream, dall, cls_idx, dsel);
  hipLaunchKernelGGL(emd_kernel, dim3(B_ * CK_), dim3(256), 0, stream,
                     qhi, qlo, gpat, cls_idx, dsel, dist);
  float* out_cls = (float*)d_out + (size_t)B_ * TK * N_ * C_;
  hipLaunchKernelGGL(sel10_kernel, dim3(B_), dim3(256), 0, stream,
                     dist, cls_idx, gcls, out_cls, nb, TK);
  int total4 = B_ * TK * (N_ * C_ / 4);
  hipLaunchKernelGGL(gather_kernel, dim3((total4 + 255) / 256), dim3(256), 0, stream,
                     gpat, nb, (float*)d_out, TK);
}